// Round 3
// baseline (135.890 us; speedup 1.0000x reference)
//
#include <hip/hip_runtime.h>
#include <math.h>

// Problem constants (fixed by the reference's setup_inputs)
#define CLS 2
#define BATCH 8
#define HH 512
#define WW 512
#define EPSV 1e-7f
#define INV_SCALE 0.125f

#define TCAP 64    // per-block compacted target list (per-batch N = 20)
#define NB 512     // atomic buckets per quantity
#define PXB 1024   // pixels per block (256 threads x 4 px)
#define NBLK (BATCH * HH * WW / PXB)  // 2048

// ws layout:
//   double gsum[4][NB]   @ 0       (16384 B)  obj_c0, obj_c1, noobj_c0, noobj_c1
//   int    gcnt[4][NB]   @ 16384   ( 8192 B)
//   int    leaf[64]      @ 24576   (  256 B)
//   int    root          @ 24832   (    4 B)
#define WS_ZERO_BYTES 24840

__global__ __launch_bounds__(256) void heatmap_main(
    const float* __restrict__ predict, const float* __restrict__ targets,
    int nT, float* __restrict__ out, double* __restrict__ gsum,
    int* __restrict__ gcnt, int* __restrict__ leaf, int* __restrict__ root)
{
    __shared__ int s_cnt;
    __shared__ float s_cos[TCAP], s_sin[TCAP];
    __shared__ float s_x3[TCAP], s_x4[TCAP], s_y3[TCAP], s_y4[TCAP];
    __shared__ int   s_cid[TCAP];

    const int tid = threadIdx.x;
    const int blockPix = blockIdx.x * PXB;
    const int b  = blockPix >> 18;             // / (H*W)
    const int r0 = (blockPix >> 9) & (HH - 1); // first of 2 rows

    if (tid == 0) s_cnt = 0;
    __syncthreads();

    // --- per-block target compaction: batch filter + 2-row interval reject ---
    // block covers gx in [0.5, 511.5], gy in [r0+0.5, r0+1.5]
    const float gyl = (float)r0 + 0.5f, gyh = (float)r0 + 1.5f;
    for (int t = tid; t < nT; t += 256) {
        const float* tp = targets + t * 7;
        if ((int)tp[0] != b) continue;
        const float cx = tp[2] * INV_SCALE, cy = tp[3] * INV_SCALE;
        const float w_ = tp[4] * INV_SCALE, h_ = tp[5] * INV_SCALE;
        const float cs = cosf(tp[6]), sn = sinf(tp[6]);
        const float x = cx * cs + cy * sn;
        const float y = -cx * sn + cy * cs;
        const float x3 = x - 0.5f * h_, x4 = x + 0.5f * h_;
        const float y3 = y - 0.5f * w_, y4 = y + 0.5f * w_;

        const float gxl = 0.5f, gxh = 511.5f;
        const float vxlo = fminf(cs * gxl, cs * gxh) + fminf(sn * gyl, sn * gyh);
        const float vxhi = fmaxf(cs * gxl, cs * gxh) + fmaxf(sn * gyl, sn * gyh);
        const float vylo = fminf(-sn * gxl, -sn * gxh) + fminf(cs * gyl, cs * gyh);
        const float vyhi = fmaxf(-sn * gxl, -sn * gxh) + fmaxf(cs * gyl, cs * gyh);

        const float M = 0.51f; // outer margin 0.5 + fp slack
        if (vxhi >= x3 - M && vxlo <= x4 + M && vyhi >= y3 - M && vylo <= y4 + M) {
            int slot = atomicAdd(&s_cnt, 1);
            s_cos[slot] = cs; s_sin[slot] = sn;
            s_x3[slot] = x3; s_x4[slot] = x4;
            s_y3[slot] = y3; s_y4[slot] = y4;
            s_cid[slot] = (int)tp[1];
        }
    }
    __syncthreads();
    const int cnt = s_cnt;

    // --- 4 lane-strided pixels per thread (all accesses coalesced) ---
    float so0 = 0.f, so1 = 0.f, sn0 = 0.f, sn1 = 0.f;
    int co0 = 0, co1 = 0, cn0 = 0, cn1 = 0;

    #pragma unroll
    for (int k = 0; k < 4; ++k) {
        const int off = tid + 256 * k;       // 0..1023 within block
        const int ro  = off >> 9;            // 0 or 1
        const int col = off & (WW - 1);
        const int row = r0 + ro;
        const float gx = (float)col + 0.5f;
        const float gy = (float)row + 0.5f;

        int objm = 0, outm = 0;
        for (int n = 0; n < cnt; ++n) {
            const float cs = s_cos[n], sn = s_sin[n];
            const float vx = cs * gx + sn * gy;
            const float vy = -sn * gx + cs * gy;
            const float x3 = s_x3[n], x4 = s_x4[n], y3 = s_y3[n], y4 = s_y4[n];
            const bool in_  = (x3 <= vx) & (vx <= x4) & (y3 <= vy) & (vy <= y4);
            const bool out_ = (x3 - 0.5f <= vx) & (vx <= x4 + 0.5f) &
                              (y3 - 0.5f <= vy) & (vy <= y4 + 0.5f);
            const int c = s_cid[n];
            objm |= ((int)in_) << c;
            outm |= ((int)out_) << c;
        }

        const int base = ((b * CLS) * HH + row) * WW + col;
        const float p0 = predict[base];
        const float p1 = predict[base + HH * WW];
        const float conf0 = __builtin_amdgcn_rcpf(1.0f + __expf(-p0));
        const float conf1 = __builtin_amdgcn_rcpf(1.0f + __expf(-p1));
        out[1 + (b * HH + row) * WW + col] = fmaxf(conf0, conf1);

        const float cc0 = fminf(fmaxf(conf0, EPSV), 1.0f - EPSV);
        const float cc1 = fminf(fmaxf(conf1, EPSV), 1.0f - EPSV);
        if (objm & 1) { so0 += __logf(cc0); co0 += 1; }
        if (objm & 2) { so1 += __logf(cc1); co1 += 1; }
        if (!(outm & 1)) { sn0 += __logf(1.0f - cc0); cn0 += 1; }
        if (!(outm & 2)) { sn1 += __logf(1.0f - cc1); cn1 += 1; }
    }

    // --- wave (64) shuffle reduction ---
    #pragma unroll
    for (int off = 32; off >= 1; off >>= 1) {
        so0 += __shfl_down(so0, off); so1 += __shfl_down(so1, off);
        sn0 += __shfl_down(sn0, off); sn1 += __shfl_down(sn1, off);
        co0 += __shfl_down(co0, off); co1 += __shfl_down(co1, off);
        cn0 += __shfl_down(cn0, off); cn1 += __shfl_down(cn1, off);
    }

    __shared__ float r_f[4][4];
    __shared__ int   r_i[4][4];
    const int wv = tid >> 6, ln = tid & 63;
    if (ln == 0) {
        r_f[wv][0] = so0; r_f[wv][1] = so1; r_f[wv][2] = sn0; r_f[wv][3] = sn1;
        r_i[wv][0] = co0; r_i[wv][1] = co1; r_i[wv][2] = cn0; r_i[wv][3] = cn1;
    }
    __syncthreads();

    __shared__ int s_isLast;
    if (tid == 0) {
        const int bkt = blockIdx.x & (NB - 1);
        float f[4]; int c[4];
        #pragma unroll
        for (int q = 0; q < 4; ++q) {
            f[q] = r_f[0][q] + r_f[1][q] + r_f[2][q] + r_f[3][q];
            c[q] = r_i[0][q] + r_i[1][q] + r_i[2][q] + r_i[3][q];
        }
        #pragma unroll
        for (int q = 0; q < 4; ++q) {
            if (f[q] != 0.f) atomicAdd(&gsum[q * NB + bkt], (double)f[q]);
            if (c[q])        atomicAdd(&gcnt[q * NB + bkt], c[q]);
        }
        __threadfence();
        int isLast = 0;
        const int lo = atomicAdd(&leaf[blockIdx.x & 63], 1);
        if (lo == (NBLK / 64) - 1) {                    // this leaf complete
            const int ro_ = atomicAdd(root, 1);
            if (ro_ == 63) isLast = 1;                  // all leaves complete
        }
        s_isLast = isLast;
    }
    __syncthreads();

    // --- fused finalize: last block reduces the buckets ---
    if (s_isLast) {
        double f[4] = {0, 0, 0, 0}; long long c[4] = {0, 0, 0, 0};
        for (int t = tid; t < NB; t += 256) {
            #pragma unroll
            for (int q = 0; q < 4; ++q) {
                f[q] += atomicAdd(&gsum[q * NB + t], 0.0);   // RMW read: coherent
                c[q] += atomicAdd(&gcnt[q * NB + t], 0);
            }
        }
        #pragma unroll
        for (int off = 32; off >= 1; off >>= 1) {
            #pragma unroll
            for (int q = 0; q < 4; ++q) {
                f[q] += __shfl_down(f[q], off);
                c[q] += __shfl_down(c[q], off);
            }
        }
        __shared__ double zf[4][4];
        __shared__ long long zi[4][4];
        if (ln == 0) {
            #pragma unroll
            for (int q = 0; q < 4; ++q) { zf[wv][q] = f[q]; zi[wv][q] = c[q]; }
        }
        __syncthreads();
        if (tid == 0) {
            double F[4]; long long C[4];
            #pragma unroll
            for (int q = 0; q < 4; ++q) {
                F[q] = zf[0][q] + zf[1][q] + zf[2][q] + zf[3][q];
                C[q] = zi[0][q] + zi[1][q] + zi[2][q] + zi[3][q];
            }
            float loss = 0.0f;
            #pragma unroll
            for (int cls = 0; cls < CLS; ++cls) {
                const long long no = C[cls], nn = C[2 + cls];
                if (no > 0) {
                    const float lo  = -(float)F[cls]     / (float)(no > 1 ? no : 1);
                    const float ln_ = -(float)F[2 + cls] / (float)(nn > 1 ? nn : 1);
                    loss += lo + ln_;   // NO_OBJ_SCALE = 1.0
                }
            }
            out[0] = loss;
        }
    }
}

extern "C" void kernel_launch(void* const* d_in, const int* in_sizes, int n_in,
                              void* d_out, int out_size, void* d_ws, size_t ws_size,
                              hipStream_t stream) {
    const float* predict = (const float*)d_in[0];
    const float* targets = (const float*)d_in[1];
    const int nT = in_sizes[1] / 7;
    float* out = (float*)d_out;
    char* ws = (char*)d_ws;
    double* gsum = (double*)ws;
    int* gcnt = (int*)(ws + 16384);
    int* leaf = (int*)(ws + 24576);
    int* root = (int*)(ws + 24832);

    hipMemsetAsync(d_ws, 0, WS_ZERO_BYTES, stream);
    heatmap_main<<<NBLK, 256, 0, stream>>>(predict, targets, nT, out,
                                           gsum, gcnt, leaf, root);
}

// Round 4
// 89.680 us; speedup vs baseline: 1.5153x; 1.5153x over previous
//
#include <hip/hip_runtime.h>
#include <math.h>

// Problem constants (fixed by the reference's setup_inputs)
#define CLS 2
#define BATCH 8
#define HH 512
#define WW 512
#define INV_SCALE 0.125f
#define LOGEPS -16.118095651f   // log(1e-7)

#define TCAP 160   // compacted per-block target list (worst case: all targets)
#define NB 512     // atomic buckets per quantity
#define TSTR 256   // SoA stride for prepped targets

// ws layout:
//   double gsum[4][NB]        @ 0      (16384 B) obj_c0, obj_c1, noobj_c0, noobj_c1
//   int    gcnt[4][NB]        @ 16384  ( 8192 B)
//   float  tprep[8][TSTR]     @ 24576  ( 8192 B) bid(i32), cid(i32), cs, sn, x3, x4, y3, y4

__global__ __launch_bounds__(512) void heatmap_prep(
    const float* __restrict__ targets, int nT,
    float* __restrict__ tprep, double* __restrict__ gsum, int* __restrict__ gcnt)
{
    const int t = threadIdx.x;
    for (int q = t; q < 4 * NB; q += 512) { gsum[q] = 0.0; gcnt[q] = 0; }
    if (t < nT) {
        const float* tp = targets + t * 7;
        const float cs = cosf(tp[6]), sn = sinf(tp[6]);
        const float cx = tp[2] * INV_SCALE, cy = tp[3] * INV_SCALE;
        const float w_ = tp[4] * INV_SCALE, h_ = tp[5] * INV_SCALE;
        const float x = cx * cs + cy * sn;
        const float y = -cx * sn + cy * cs;
        ((int*)tprep)[0 * TSTR + t] = (int)tp[0];
        ((int*)tprep)[1 * TSTR + t] = (int)tp[1];
        tprep[2 * TSTR + t] = cs;
        tprep[3 * TSTR + t] = sn;
        tprep[4 * TSTR + t] = x - 0.5f * h_;
        tprep[5 * TSTR + t] = x + 0.5f * h_;
        tprep[6 * TSTR + t] = y - 0.5f * w_;
        tprep[7 * TSTR + t] = y + 0.5f * w_;
    }
}

__global__ __launch_bounds__(256) void heatmap_main(
    const float* __restrict__ predict, const float* __restrict__ tprep,
    int nT, float* __restrict__ out, double* __restrict__ gsum,
    int* __restrict__ gcnt)
{
    __shared__ int s_cnt;
    __shared__ float s_cos[TCAP], s_sin[TCAP];
    __shared__ float s_x3[TCAP], s_x4[TCAP], s_y3[TCAP], s_y4[TCAP];
    __shared__ int   s_cid[TCAP];

    const int tid = threadIdx.x;
    const int blockPix = blockIdx.x * 256;
    const int b  = blockPix >> 18;             // / (H*W)
    const int i  = (blockPix >> 9) & (HH - 1); // row
    const int j0 = blockPix & (WW - 1);        // strip start (0 or 256)

    if (tid == 0) s_cnt = 0;
    __syncthreads();

    const float gy = (float)i + 0.5f;

    // --- per-block target compaction (prepped SoA; nT <= 256, single pass) ---
    if (tid < nT && ((const int*)tprep)[tid] == b) {
        const float cs = tprep[2 * TSTR + tid], sn = tprep[3 * TSTR + tid];
        const float x3 = tprep[4 * TSTR + tid], x4 = tprep[5 * TSTR + tid];
        const float y3 = tprep[6 * TSTR + tid], y4 = tprep[7 * TSTR + tid];

        // strip gx in [j0+0.5, j0+255.5], gy fixed -> exact vx/vy intervals
        const float gxl = (float)j0 + 0.5f, gxh = (float)j0 + 255.5f;
        const float a1 = cs * gxl + sn * gy, a2 = cs * gxh + sn * gy;
        const float vxlo = fminf(a1, a2), vxhi = fmaxf(a1, a2);
        const float b1 = -sn * gxl + cs * gy, b2 = -sn * gxh + cs * gy;
        const float vylo = fminf(b1, b2), vyhi = fmaxf(b1, b2);

        const float M = 0.51f; // outer margin 0.5 + fp slack
        if (vxhi >= x3 - M && vxlo <= x4 + M && vyhi >= y3 - M && vylo <= y4 + M) {
            int slot = atomicAdd(&s_cnt, 1);
            s_cos[slot] = cs; s_sin[slot] = sn;
            s_x3[slot] = x3; s_x4[slot] = x4;
            s_y3[slot] = y3; s_y4[slot] = y4;
            s_cid[slot] = ((const int*)tprep)[TSTR + tid];
        }
    }
    __syncthreads();
    const int cnt = s_cnt;

    // --- per-pixel mask evaluation ---
    const int j = j0 + tid;
    const float gx = (float)j + 0.5f;
    int objm = 0, outm = 0;
    for (int n = 0; n < cnt; ++n) {
        const float cs = s_cos[n], sn = s_sin[n];
        const float vx = cs * gx + sn * gy;
        const float vy = -sn * gx + cs * gy;
        const float x3 = s_x3[n], x4 = s_x4[n], y3 = s_y3[n], y4 = s_y4[n];
        const bool in_  = (x3 <= vx) & (vx <= x4) & (y3 <= vy) & (vy <= y4);
        const bool out_ = (x3 - 0.5f <= vx) & (vx <= x4 + 0.5f) &
                          (y3 - 0.5f <= vy) & (vy <= y4 + 0.5f);
        const int c = s_cid[n];
        objm |= ((int)in_) << c;
        outm |= ((int)out_) << c;
    }

    // --- sigmoid + shared-softplus logs ---
    // conf = e^p/(1+e^p); log(1-conf) = -log(1+e^p); log(conf) = p + log(1-conf)
    const int base = (b * CLS * HH + i) * WW + j;
    const float p0 = predict[base];
    const float p1 = predict[base + HH * WW];
    const float t0 = __expf(p0), t1 = __expf(p1);
    const float s0 = 1.0f + t0,  s1 = 1.0f + t1;
    const float c0 = t0 * __builtin_amdgcn_rcpf(s0);
    const float c1 = t1 * __builtin_amdgcn_rcpf(s1);
    float l10 = -__logf(s0);                    // log(1-conf0)
    float l11 = -__logf(s1);
    const float lc0 = fmaxf(p0 + l10, LOGEPS);  // log(conf0), EPS-clipped
    const float lc1 = fmaxf(p1 + l11, LOGEPS);
    l10 = fmaxf(l10, LOGEPS);
    l11 = fmaxf(l11, LOGEPS);

    out[1 + (b * HH + i) * WW + j] = fmaxf(c0, c1);

    // --- per-thread loss terms; counts via ballot/popcount ---
    float so0 = (objm & 1) ? lc0 : 0.0f;
    float so1 = (objm & 2) ? lc1 : 0.0f;
    float sn0 = (outm & 1) ? 0.0f : l10;
    float sn1 = (outm & 2) ? 0.0f : l11;
    const int co0 = (int)__popcll(__ballot(objm & 1));
    const int co1 = (int)__popcll(__ballot(objm & 2));
    const int cn0 = (int)__popcll(__ballot(!(outm & 1)));
    const int cn1 = (int)__popcll(__ballot(!(outm & 2)));

    // --- wave (64) shuffle reduction: 4 float trees only ---
    #pragma unroll
    for (int off = 32; off >= 1; off >>= 1) {
        so0 += __shfl_down(so0, off); so1 += __shfl_down(so1, off);
        sn0 += __shfl_down(sn0, off); sn1 += __shfl_down(sn1, off);
    }

    __shared__ float r_f[4][4];
    __shared__ int   r_i[4][4];
    const int wv = tid >> 6, ln = tid & 63;
    if (ln == 0) {
        r_f[wv][0] = so0; r_f[wv][1] = so1; r_f[wv][2] = sn0; r_f[wv][3] = sn1;
        r_i[wv][0] = co0; r_i[wv][1] = co1; r_i[wv][2] = cn0; r_i[wv][3] = cn1;
    }
    __syncthreads();
    if (tid == 0) {
        const int bkt = blockIdx.x & (NB - 1);
        #pragma unroll
        for (int q = 0; q < 4; ++q) {
            const float f = r_f[0][q] + r_f[1][q] + r_f[2][q] + r_f[3][q];
            const int   c = r_i[0][q] + r_i[1][q] + r_i[2][q] + r_i[3][q];
            if (f != 0.0f) atomicAdd(&gsum[q * NB + bkt], (double)f);
            if (c)         atomicAdd(&gcnt[q * NB + bkt], c);
        }
    }
}

__global__ __launch_bounds__(512) void heatmap_finalize(
    const double* __restrict__ gsum, const int* __restrict__ gcnt,
    float* __restrict__ out)
{
    const int t = threadIdx.x;          // 0..511 == one bucket each
    double f[4]; int c[4];
    #pragma unroll
    for (int q = 0; q < 4; ++q) { f[q] = gsum[q * NB + t]; c[q] = gcnt[q * NB + t]; }

    #pragma unroll
    for (int off = 32; off >= 1; off >>= 1) {
        #pragma unroll
        for (int q = 0; q < 4; ++q) {
            f[q] += __shfl_down(f[q], off);
            c[q] += __shfl_down(c[q], off);
        }
    }

    __shared__ double sf[8][4];
    __shared__ int    si[8][4];
    const int wv = t >> 6, ln = t & 63;
    if (ln == 0) {
        #pragma unroll
        for (int q = 0; q < 4; ++q) { sf[wv][q] = f[q]; si[wv][q] = c[q]; }
    }
    __syncthreads();
    if (t == 0) {
        double F[4] = {0, 0, 0, 0}; int C[4] = {0, 0, 0, 0};
        for (int w = 0; w < 8; ++w)
            #pragma unroll
            for (int q = 0; q < 4; ++q) { F[q] += sf[w][q]; C[q] += si[w][q]; }
        float loss = 0.0f;
        #pragma unroll
        for (int cls = 0; cls < CLS; ++cls) {
            const int no = C[cls];
            const int nn = C[2 + cls];
            if (no > 0) {
                const float lo  = -(float)F[cls]     / (float)(no > 1 ? no : 1);
                const float ln_ = -(float)F[2 + cls] / (float)(nn > 1 ? nn : 1);
                loss += lo + ln_;  // NO_OBJ_SCALE = 1.0
            }
        }
        out[0] = loss;
    }
}

extern "C" void kernel_launch(void* const* d_in, const int* in_sizes, int n_in,
                              void* d_out, int out_size, void* d_ws, size_t ws_size,
                              hipStream_t stream) {
    const float* predict = (const float*)d_in[0];
    const float* targets = (const float*)d_in[1];
    const int nT = in_sizes[1] / 7;
    float* out = (float*)d_out;
    char* ws = (char*)d_ws;
    double* gsum = (double*)ws;
    int* gcnt = (int*)(ws + 16384);
    float* tprep = (float*)(ws + 24576);

    heatmap_prep<<<1, 512, 0, stream>>>(targets, nT, tprep, gsum, gcnt);
    const int pixels = BATCH * HH * WW;
    heatmap_main<<<pixels / 256, 256, 0, stream>>>(predict, tprep, nT, out,
                                                   gsum, gcnt);
    heatmap_finalize<<<1, 512, 0, stream>>>(gsum, gcnt, out);
}

// Round 5
// 80.862 us; speedup vs baseline: 1.6805x; 1.1090x over previous
//
#include <hip/hip_runtime.h>
#include <math.h>

// Problem constants (fixed by the reference's setup_inputs)
#define CLS 2
#define BATCH 8
#define HH 512
#define WW 512
#define INV_SCALE 0.125f
#define LOGEPS -16.118095651f   // log(1e-7)

#define NB 512      // atomic buckets per quantity
#define TSTRIDE 192 // per-batch SoA stride (capacity; nT<=160 total)
#define TCAP 192    // LDS compacted-target capacity

// ws layout:
//   double gsum[4][NB]            @ 0      (16384 B) obj_c0, obj_c1, noobj_c0, noobj_c1
//   int    gcnt[4][NB]            @ 16384  ( 8192 B)
//   int    bcnt[8]                @ 24576  (   32 B)
//   float  tdat[8][7][TSTRIDE]    @ 24608  (43008 B) cs,sn,x3,x4,y3,y4,cid per batch

__global__ __launch_bounds__(256) void heatmap_prep(
    const float* __restrict__ targets, int nT, double* __restrict__ gsum,
    int* __restrict__ gcnt, int* __restrict__ bcnt, float* __restrict__ tdat)
{
    __shared__ int s_b[BATCH];
    const int t = threadIdx.x;
    if (t < BATCH) s_b[t] = 0;
    for (int q = t; q < 4 * NB; q += 256) { gsum[q] = 0.0; gcnt[q] = 0; }
    __syncthreads();
    if (t < nT) {
        const float* tp = targets + t * 7;
        const int b = (int)tp[0];
        const float cs = cosf(tp[6]), sn = sinf(tp[6]);
        const float cx = tp[2] * INV_SCALE, cy = tp[3] * INV_SCALE;
        const float w_ = tp[4] * INV_SCALE, h_ = tp[5] * INV_SCALE;
        const float x = cx * cs + cy * sn;
        const float y = -cx * sn + cy * cs;
        const int slot = atomicAdd(&s_b[b], 1);
        float* tb = tdat + b * (7 * TSTRIDE);
        tb[0 * TSTRIDE + slot] = cs;
        tb[1 * TSTRIDE + slot] = sn;
        tb[2 * TSTRIDE + slot] = x - 0.5f * h_;
        tb[3 * TSTRIDE + slot] = x + 0.5f * h_;
        tb[4 * TSTRIDE + slot] = y - 0.5f * w_;
        tb[5 * TSTRIDE + slot] = y + 0.5f * w_;
        ((int*)tb)[6 * TSTRIDE + slot] = (int)tp[1];
    }
    __syncthreads();
    if (t < BATCH) bcnt[t] = s_b[t];
}

// 64 threads/block (1 wave), 4 contiguous px/thread, 256-px row strip per block.
__global__ __launch_bounds__(64) void heatmap_main(
    const float* __restrict__ predict, float* __restrict__ out,
    double* __restrict__ gsum, int* __restrict__ gcnt,
    const int* __restrict__ bcnt, const float* __restrict__ tdat)
{
    __shared__ float s_cs[TCAP], s_sn[TCAP];
    __shared__ float s_x3[TCAP], s_x4[TCAP], s_y3[TCAP], s_y4[TCAP];
    __shared__ int   s_cid[TCAP];

    const int l = threadIdx.x;
    const int blockPix = blockIdx.x * 256;
    const int b  = blockPix >> 18;             // / (H*W)
    const int i  = (blockPix >> 9) & (HH - 1); // row
    const int j0 = blockPix & (WW - 1);        // 0 or 256
    const float gy = (float)i + 0.5f;

    // --- compaction from per-batch prepped SoA: ballot-prefix, no atomics ---
    const int nb = bcnt[b];
    const float* tb = tdat + b * (7 * TSTRIDE);
    int cnt = 0;
    for (int base = 0; base < nb; base += 64) {
        bool acc = false;
        float cs = 0.f, sn = 0.f, x3 = 0.f, x4 = 0.f, y3 = 0.f, y4 = 0.f;
        int cid = 0;
        const int t = base + l;
        if (t < nb) {
            cs = tb[0 * TSTRIDE + t]; sn = tb[1 * TSTRIDE + t];
            x3 = tb[2 * TSTRIDE + t]; x4 = tb[3 * TSTRIDE + t];
            y3 = tb[4 * TSTRIDE + t]; y4 = tb[5 * TSTRIDE + t];
            cid = ((const int*)tb)[6 * TSTRIDE + t];
            // strip: gx in [j0+0.5, j0+255.5], gy fixed -> exact vx/vy intervals
            const float gxl = (float)j0 + 0.5f, gxh = (float)j0 + 255.5f;
            const float a1 = cs * gxl + sn * gy, a2 = cs * gxh + sn * gy;
            const float b1 = -sn * gxl + cs * gy, b2 = -sn * gxh + cs * gy;
            const float vxlo = fminf(a1, a2), vxhi = fmaxf(a1, a2);
            const float vylo = fminf(b1, b2), vyhi = fmaxf(b1, b2);
            const float M = 0.51f; // outer margin 0.5 + fp slack
            acc = (vxhi >= x3 - M) & (vxlo <= x4 + M) &
                  (vyhi >= y3 - M) & (vylo <= y4 + M);
        }
        const unsigned long long bal = __ballot(acc);
        if (acc) {
            const int slot = cnt + (int)__popcll(bal & ((1ull << l) - 1ull));
            s_cs[slot] = cs; s_sn[slot] = sn;
            s_x3[slot] = x3; s_x4[slot] = x4;
            s_y3[slot] = y3; s_y4[slot] = y4;
            s_cid[slot] = cid;
        }
        cnt += (int)__popcll(bal);
    }
    __syncthreads();  // single wave: cheap; orders LDS writes before reads

    // --- masks for 4 contiguous pixels (vx,vy incremental along gx) ---
    const int j = j0 + 4 * l;
    const float gxb = (float)j + 0.5f;
    int objm[4] = {0, 0, 0, 0}, outm[4] = {0, 0, 0, 0};
    for (int n = 0; n < cnt; ++n) {      // cnt is wave-uniform; usually 0
        const float cs = s_cs[n], sn = s_sn[n];
        const float x3 = s_x3[n], x4 = s_x4[n], y3 = s_y3[n], y4 = s_y4[n];
        const int cbit = 1 << s_cid[n];
        float vx = cs * gxb + sn * gy;
        float vy = -sn * gxb + cs * gy;
        #pragma unroll
        for (int k = 0; k < 4; ++k) {
            const bool in_  = (x3 <= vx) & (vx <= x4) & (y3 <= vy) & (vy <= y4);
            const bool out_ = (x3 - 0.5f <= vx) & (vx <= x4 + 0.5f) &
                              (y3 - 0.5f <= vy) & (vy <= y4 + 0.5f);
            if (in_)  objm[k] |= cbit;
            if (out_) outm[k] |= cbit;
            vx += cs; vy -= sn;
        }
    }

    // --- vectorized loads; sigmoid/log algebra (5 transcendentals/px) ---
    const int pbase = (b * CLS * HH + i) * WW + j;   // 16B-aligned (j = 4l)
    const float4 P0 = *(const float4*)(predict + pbase);
    const float4 P1 = *(const float4*)(predict + pbase + HH * WW);

    float so0 = 0.f, so1 = 0.f, sq0 = 0.f, sq1 = 0.f;
    int c_obj0 = 0, c_obj1 = 0, c_no0 = 0, c_no1 = 0;
    float hm[4];
    #pragma unroll
    for (int k = 0; k < 4; ++k) {
        const float p0 = (&P0.x)[k], p1 = (&P1.x)[k];
        const float t0 = __expf(p0), t1 = __expf(p1);
        const float l0n = -__logf(1.0f + t0);   // log(1-conf0)
        const float l1n = -__logf(1.0f + t1);
        const float lc0 = fmaxf(p0 + l0n, LOGEPS);  // log(conf0), EPS-clipped
        const float lc1 = fmaxf(p1 + l1n, LOGEPS);
        const float l0c = fmaxf(l0n, LOGEPS);
        const float l1c = fmaxf(l1n, LOGEPS);
        const float tm = fmaxf(t0, t1);
        hm[k] = tm * __builtin_amdgcn_rcpf(1.0f + tm);  // sigmoid(max(p0,p1))
        const int om = objm[k], um = outm[k];
        if (om & 1) { so0 += lc0; ++c_obj0; }
        if (om & 2) { so1 += lc1; ++c_obj1; }
        if (!(um & 1)) { sq0 += l0c; ++c_no0; }
        if (!(um & 2)) { sq1 += l1c; ++c_no1; }
    }

    float* ho = out + 1 + (b * HH + i) * WW + j;  // +1: misaligned -> 4 dwords
    ho[0] = hm[0]; ho[1] = hm[1]; ho[2] = hm[2]; ho[3] = hm[3];

    // --- wave reduction; obj trees skipped wave-uniformly when empty ---
    const unsigned long long anyobj =
        __ballot((objm[0] | objm[1] | objm[2] | objm[3]) != 0);
    int pc = (c_no0 & 0xffff) | (c_no1 << 16);
    #pragma unroll
    for (int off = 32; off >= 1; off >>= 1) {
        sq0 += __shfl_down(sq0, off);
        sq1 += __shfl_down(sq1, off);
        pc  += __shfl_down(pc, off);
    }
    int po = 0;
    if (anyobj) {
        po = (c_obj0 & 0xffff) | (c_obj1 << 16);
        #pragma unroll
        for (int off = 32; off >= 1; off >>= 1) {
            so0 += __shfl_down(so0, off);
            so1 += __shfl_down(so1, off);
            po  += __shfl_down(po, off);
        }
    }
    if (l == 0) {
        const int bkt = blockIdx.x & (NB - 1);
        atomicAdd(&gsum[2 * NB + bkt], (double)sq0);
        atomicAdd(&gsum[3 * NB + bkt], (double)sq1);
        atomicAdd(&gcnt[2 * NB + bkt], pc & 0xffff);
        atomicAdd(&gcnt[3 * NB + bkt], pc >> 16);
        if (anyobj) {
            const int o0 = po & 0xffff, o1 = po >> 16;
            if (o0) { atomicAdd(&gsum[0 * NB + bkt], (double)so0);
                      atomicAdd(&gcnt[0 * NB + bkt], o0); }
            if (o1) { atomicAdd(&gsum[1 * NB + bkt], (double)so1);
                      atomicAdd(&gcnt[1 * NB + bkt], o1); }
        }
    }
}

__global__ __launch_bounds__(512) void heatmap_finalize(
    const double* __restrict__ gsum, const int* __restrict__ gcnt,
    float* __restrict__ out)
{
    const int t = threadIdx.x;          // 0..511 == one bucket each
    double f[4]; int c[4];
    #pragma unroll
    for (int q = 0; q < 4; ++q) { f[q] = gsum[q * NB + t]; c[q] = gcnt[q * NB + t]; }

    #pragma unroll
    for (int off = 32; off >= 1; off >>= 1) {
        #pragma unroll
        for (int q = 0; q < 4; ++q) {
            f[q] += __shfl_down(f[q], off);
            c[q] += __shfl_down(c[q], off);
        }
    }

    __shared__ double sf[8][4];
    __shared__ int    si[8][4];
    const int wv = t >> 6, ln = t & 63;
    if (ln == 0) {
        #pragma unroll
        for (int q = 0; q < 4; ++q) { sf[wv][q] = f[q]; si[wv][q] = c[q]; }
    }
    __syncthreads();
    if (t == 0) {
        double F[4] = {0, 0, 0, 0}; int C[4] = {0, 0, 0, 0};
        for (int w = 0; w < 8; ++w)
            #pragma unroll
            for (int q = 0; q < 4; ++q) { F[q] += sf[w][q]; C[q] += si[w][q]; }
        float loss = 0.0f;
        #pragma unroll
        for (int cls = 0; cls < CLS; ++cls) {
            const int no = C[cls];
            const int nn = C[2 + cls];
            if (no > 0) {
                const float lo  = -(float)F[cls]     / (float)(no > 1 ? no : 1);
                const float ln_ = -(float)F[2 + cls] / (float)(nn > 1 ? nn : 1);
                loss += lo + ln_;  // NO_OBJ_SCALE = 1.0
            }
        }
        out[0] = loss;
    }
}

extern "C" void kernel_launch(void* const* d_in, const int* in_sizes, int n_in,
                              void* d_out, int out_size, void* d_ws, size_t ws_size,
                              hipStream_t stream) {
    const float* predict = (const float*)d_in[0];
    const float* targets = (const float*)d_in[1];
    const int nT = in_sizes[1] / 7;
    float* out = (float*)d_out;
    char* ws = (char*)d_ws;
    double* gsum = (double*)ws;
    int* gcnt = (int*)(ws + 16384);
    int* bcnt = (int*)(ws + 24576);
    float* tdat = (float*)(ws + 24608);

    heatmap_prep<<<1, 256, 0, stream>>>(targets, nT, gsum, gcnt, bcnt, tdat);
    const int pixels = BATCH * HH * WW;
    heatmap_main<<<pixels / 256, 64, 0, stream>>>(predict, out, gsum, gcnt,
                                                  bcnt, tdat);
    heatmap_finalize<<<1, 512, 0, stream>>>(gsum, gcnt, out);
}